// Round 21
// baseline (67.950 us; speedup 1.0000x reference)
//
#include <hip/hip_runtime.h>
#include <hip/hip_bf16.h>

// GAT layer, N=4096, FIN=512, H=4 heads, F=64.
// R21: R20 base (best, 64.5) + ONE change: K3 cc-loop unroll 4->8.
// Same lever as R20 (+3.3us): K3 is grid-capped at 2 blocks/CU, VGPR free;
// deeper unroll batches more in-flight mask/f2/V loads per wave. Expected
// diminishing returns; clean revert anchor if neutral.
//   K01: blocks<512 = GEMM 32x64/2x4-micro + scores + u16-padded V-transpose;
//        blocks>=512 = grid-stride ballot mask-pack. (R12/R18 exact)
//   K3:  64 rows/block, 20 MFMA/cc, trunc-packed P, raw v_exp_f32,
//        no max-subtraction (scores bounded -> exact); bf16 partials; unroll 8.
//   K4:  combine njb bf16 partials, normalize, ELU. (R18)
// ws: pacc16 njb*2MB | f1h | f2h | Vhi 2MB | plsum | Ab 2MB. njb: 8 else 4.

#define NN   4096
#define FIN  512
#define H    4
#define F    64
#define HF   256
#define LOG2E 1.44269504088896340736f

typedef __attribute__((ext_vector_type(4))) float f32x4;
typedef __attribute__((ext_vector_type(8))) short short8;

union U8 { short8 s; unsigned int w[4]; };

// ---------------- K01: fused (GEMM+scores+transpose) | mask-pack ----------
// grid 1536: blocks 0..511 = gemm (bi = b&127, h = b>>7), 512..1535 = pack.
__global__ __launch_bounds__(256) void gemm_scores_pack(
        const float* __restrict__ X, const float* __restrict__ W,
        const float* __restrict__ a_src, const float* __restrict__ a_dst,
        const int* __restrict__ A,
        float* __restrict__ f1h, float* __restrict__ f2h,
        unsigned short* __restrict__ Vhi,
        unsigned long long* __restrict__ Ab) {
    if (blockIdx.x >= 512) {
        const int pb   = blockIdx.x - 512;                    // 0..1023
        const int gw   = (pb * 256 + threadIdx.x) >> 6;
        const int lane = threadIdx.x & 63;
        const int nchunk = NN * NN / 64;                      // 262144
        for (int c = gw; c < nchunk; c += 4096) {
            int a = A[(size_t)c * 64 + lane];
            unsigned long long m = __ballot(a != 0);
            if (lane == 0) Ab[c] = m;
        }
        return;
    }

    __shared__ float Ast[32][34];            // [k][m]
    __shared__ float Bs[32][64];             // [k][n]
    __shared__ unsigned short Vt[64][40];    // [f][n]

    const int bi = blockIdx.x & 127, h = blockIdx.x >> 7;
    const int t  = threadIdx.x;
    const int tx = t & 15, ty = t >> 4;

    float acc[2][4];
#pragma unroll
    for (int r = 0; r < 2; ++r)
#pragma unroll
        for (int c = 0; c < 4; ++c) acc[r][c] = 0.f;

    const int ar = t >> 3, ak = (t & 7) * 4;
    const int bk = t >> 3, bn = (t & 7) * 8;

    const float* Ap = X + (size_t)(bi * 32 + ar) * FIN + ak;
    const float* Bp = W + (size_t)bk * HF + h * F + bn;

    for (int k0 = 0; k0 < FIN; k0 += 32) {
        float4 av  = *(const float4*)(Ap + k0);
        float4 bv0 = *(const float4*)(Bp + (size_t)k0 * HF);
        float4 bv1 = *(const float4*)(Bp + (size_t)k0 * HF + 4);
        __syncthreads();
        Ast[ak + 0][ar] = av.x;
        Ast[ak + 1][ar] = av.y;
        Ast[ak + 2][ar] = av.z;
        Ast[ak + 3][ar] = av.w;
        *(float4*)&Bs[bk][bn] = bv0;
        *(float4*)&Bs[bk][bn + 4] = bv1;
        __syncthreads();
#pragma unroll
        for (int kk = 0; kk < 32; ++kk) {
            float2 a2 = *(const float2*)&Ast[kk][ty * 2];
            float4 b4 = *(const float4*)&Bs[kk][tx * 4];
            acc[0][0] += a2.x * b4.x; acc[0][1] += a2.x * b4.y;
            acc[0][2] += a2.x * b4.z; acc[0][3] += a2.x * b4.w;
            acc[1][0] += a2.y * b4.x; acc[1][1] += a2.y * b4.y;
            acc[1][2] += a2.y * b4.z; acc[1][3] += a2.y * b4.w;
        }
    }

    // scores: per-row dot with a_src/a_dst, reduce over 16 tx lanes
    float4 as4 = *(const float4*)(a_src + h * F + tx * 4);
    float4 ad4 = *(const float4*)(a_dst + h * F + tx * 4);
#pragma unroll
    for (int r = 0; r < 2; ++r) {
        float s1 = acc[r][0] * as4.x + acc[r][1] * as4.y
                 + acc[r][2] * as4.z + acc[r][3] * as4.w;
        float s2 = acc[r][0] * ad4.x + acc[r][1] * ad4.y
                 + acc[r][2] * ad4.z + acc[r][3] * ad4.w;
#pragma unroll
        for (int off = 1; off < 16; off <<= 1) {
            s1 += __shfl_xor(s1, off, 16);
            s2 += __shfl_xor(s2, off, 16);
        }
        if (tx == 0) {
            const int n = bi * 32 + ty * 2 + r;
            f1h[h * NN + n] = s1 * LOG2E;
            f2h[h * NN + n] = s2 * LOG2E;
        }
    }

    // transposed bf16 V via LDS bounce
    __syncthreads();
#pragma unroll
    for (int r = 0; r < 2; ++r)
#pragma unroll
        for (int c = 0; c < 4; ++c) {
            __hip_bfloat16 b = __float2bfloat16(acc[r][c]);
            Vt[tx * 4 + c][ty * 2 + r] = __builtin_bit_cast(unsigned short, b);
        }
    __syncthreads();
    {
        const int f = t >> 2, ch = t & 3;
        short8 v = *(const short8*)&Vt[f][ch * 8];
        *(short8*)&Vhi[(size_t)(h * F + f) * NN + bi * 32 + ch * 8] = v;
    }
}

// ---------------- K3: MFMA fused attention (bf16 partials) ----------------
// grid (64, njb): ib = 64-row block (4 rowtiles), jb = JLEN strip. wave=head.
template <int JLEN>
__global__ __launch_bounds__(256) void gat_attn_mfma(
        const unsigned int* __restrict__ Ab32,
        const unsigned short* __restrict__ Vhi,
        const float* __restrict__ f1h, const float* __restrict__ f2h,
        unsigned short* __restrict__ pacc16, float* __restrict__ plsum) {
    constexpr int NCC = JLEN / 32;
    const int ib = blockIdx.x, jb = blockIdx.y;
    const int h    = threadIdx.x >> 6;
    const int lane = threadIdx.x & 63;
    const int il = lane & 15;        // MFMA A row / B,C/D col
    const int kg = lane >> 4;        // k-group
    const int sh = kg * 8;
    const int ibase = ib * 64 + il;

    float c[4];
#pragma unroll
    for (int rt = 0; rt < 4; ++rt) c[rt] = f1h[h * NN + ibase + rt * 16];

    const unsigned int* abp[4];
#pragma unroll
    for (int rt = 0; rt < 4; ++rt)
        abp[rt] = Ab32 + (size_t)(ibase + rt * 16) * (NN / 32) + jb * (JLEN / 32);

    const float* f2b = f2h + (size_t)h * NN + jb * JLEN + sh;

    const unsigned short* vb[4];
#pragma unroll
    for (int ft = 0; ft < 4; ++ft)
        vb[ft] = Vhi + (size_t)(h * F + ft * 16 + il) * NN + jb * JLEN + sh;

    f32x4 acc[4][4], lac[4];
#pragma unroll
    for (int rt = 0; rt < 4; ++rt) {
        lac[rt] = (f32x4){0.f, 0.f, 0.f, 0.f};
#pragma unroll
        for (int ft = 0; ft < 4; ++ft) acc[rt][ft] = (f32x4){0.f, 0.f, 0.f, 0.f};
    }

    short8 ones;
#pragma unroll
    for (int e = 0; e < 8; ++e) ones[e] = (short)0x3F80;   // bf16 1.0

#pragma unroll 8
    for (int cc = 0; cc < NCC; ++cc) {
        unsigned int m[4];
#pragma unroll
        for (int rt = 0; rt < 4; ++rt) m[rt] = abp[rt][cc] >> sh;

        float4 ga = *(const float4*)(f2b + cc * 32);
        float4 gb = *(const float4*)(f2b + cc * 32 + 4);
        float gv[8] = {ga.x, ga.y, ga.z, ga.w, gb.x, gb.y, gb.z, gb.w};

        short8 bh[4];
#pragma unroll
        for (int ft = 0; ft < 4; ++ft)
            bh[ft] = *reinterpret_cast<const short8*>(vb[ft] + cc * 32);

#pragma unroll
        for (int rt = 0; rt < 4; ++rt) {
            float pf[8];
#pragma unroll
            for (int e = 0; e < 8; ++e) {
                float s = c[rt] + gv[e];
                s = fmaxf(s, 0.2f * s);                 // leaky relu
                float q = __builtin_amdgcn_exp2f(s);    // raw v_exp_f32
                pf[e] = ((m[rt] >> e) & 1u) ? q : 0.f;
            }
            U8 pa;
#pragma unroll
            for (int e = 0; e < 8; e += 2)
                pa.w[e >> 1] = __builtin_amdgcn_perm(__float_as_uint(pf[e + 1]),
                                                     __float_as_uint(pf[e]),
                                                     0x07060302u);
#pragma unroll
            for (int ft = 0; ft < 4; ++ft)
                acc[rt][ft] = __builtin_amdgcn_mfma_f32_16x16x32_bf16(
                    pa.s, bh[ft], acc[rt][ft], 0, 0, 0);
            lac[rt] = __builtin_amdgcn_mfma_f32_16x16x32_bf16(
                pa.s, ones, lac[rt], 0, 0, 0);
        }
    }

    // C/D layout: col = lane&15, row = (lane>>4)*4 + reg. RNE-bf16 partials.
    unsigned short* pb = pacc16 + (size_t)jb * NN * HF + (size_t)(ib * 64) * HF;
#pragma unroll
    for (int rt = 0; rt < 4; ++rt)
#pragma unroll
        for (int ft = 0; ft < 4; ++ft)
#pragma unroll
            for (int r = 0; r < 4; ++r) {
                __hip_bfloat16 b = __float2bfloat16(acc[rt][ft][r]);
                pb[(rt * 16 + kg * 4 + r) * HF + h * F + ft * 16 + il] =
                    __builtin_bit_cast(unsigned short, b);
            }

    if (il == 0) {   // ones-MFMA: every col holds the row sum; use col 0
#pragma unroll
        for (int rt = 0; rt < 4; ++rt)
#pragma unroll
            for (int r = 0; r < 4; ++r)
                plsum[(size_t)jb * NN * H
                      + (size_t)(ib * 64 + rt * 16 + kg * 4 + r) * H + h] = lac[rt][r];
    }
}

// ---------------- K4: combine bf16 partials, normalize, ELU ----------
__global__ __launch_bounds__(256) void finalize(
        const unsigned short* __restrict__ pacc16,
        const float* __restrict__ plsum,
        const unsigned short* __restrict__ Vhi, float* __restrict__ out,
        int njb) {
    const int gid4 = blockIdx.x * 256 + threadIdx.x;   // 0 .. NN*HF/4-1
    const int i = gid4 >> 6, q = gid4 & 63;
    const int h = q >> 4;
    float av[4] = {0.f, 0.f, 0.f, 0.f};
    float l = 0.f;
    for (int jb = 0; jb < njb; ++jb) {
        ushort4 p = *(const ushort4*)&pacc16[(size_t)jb * NN * HF
                                             + (size_t)i * HF + q * 4];
        av[0] += __uint_as_float((unsigned)p.x << 16);
        av[1] += __uint_as_float((unsigned)p.y << 16);
        av[2] += __uint_as_float((unsigned)p.z << 16);
        av[3] += __uint_as_float((unsigned)p.w << 16);
        l += plsum[(size_t)jb * NN * H + (size_t)i * H + h];
    }
    if (l == 0.f) {   // empty row: reference softmax degenerates to uniform
#pragma unroll
        for (int c = 0; c < 4; ++c) {
            const unsigned short* col = Vhi + (size_t)(q * 4 + c) * NN;
            float s = 0.f;
            for (int j = 0; j < NN; ++j)
                s += __uint_as_float(((unsigned int)col[j]) << 16);
            av[c] = s;
        }
        l = (float)NN;
    }
    const float rl = 1.0f / l;
    float4 o;
    float* op = &o.x;
#pragma unroll
    for (int c = 0; c < 4; ++c) {
        float v = av[c] * rl;
        op[c] = (v > 0.f) ? v : (__builtin_amdgcn_exp2f(v * LOG2E) - 1.f);
    }
    *(float4*)&out[(size_t)i * HF + q * 4] = o;
}

// ---------------- launch ----------------
extern "C" void kernel_launch(void* const* d_in, const int* in_sizes, int n_in,
                              void* d_out, int out_size, void* d_ws, size_t ws_size,
                              hipStream_t stream) {
    const float* X     = (const float*)d_in[0];
    const int*   A     = (const int*)d_in[1];
    const float* W     = (const float*)d_in[2];
    const float* a_src = (const float*)d_in[3];
    const float* a_dst = (const float*)d_in[4];
    float* out = (float*)d_out;

    // ws: pacc16 njb*NN*HF*2 | f1h,f2h | Vhi HF*NN*2 | plsum | Ab NN*NN/8
    const size_t fixed = (size_t)2 * NN * H * 4 + (size_t)HF * NN * 2
                       + (size_t)NN * NN / 8;
    auto need = [&](int njb) {
        return (size_t)njb * NN * HF * 2 + (size_t)njb * NN * H * 4 + fixed;
    };
    const int njb = (ws_size >= need(8)) ? 8 : 4;   // deterministic in ws_size

    unsigned short* pacc16 = (unsigned short*)d_ws;
    float* f1h  = (float*)(pacc16 + (size_t)njb * NN * HF);
    float* f2h  = f1h + (size_t)NN * H;
    unsigned short* Vhi = (unsigned short*)(f2h + (size_t)NN * H);
    float* plsum = (float*)(Vhi + (size_t)HF * NN);
    unsigned long long* Ab = (unsigned long long*)(plsum + (size_t)njb * NN * H);

    gemm_scores_pack<<<1536, 256, 0, stream>>>(X, W, a_src, a_dst, A,
                                               f1h, f2h, Vhi, Ab);
    if (njb == 8)
        gat_attn_mfma<512><<<dim3(64, 8), 256, 0, stream>>>(
            (const unsigned int*)Ab, Vhi, f1h, f2h, pacc16, plsum);
    else
        gat_attn_mfma<1024><<<dim3(64, 4), 256, 0, stream>>>(
            (const unsigned int*)Ab, Vhi, f1h, f2h, pacc16, plsum);
    finalize<<<NN * HF / 4 / 256, 256, 0, stream>>>(pacc16, plsum, Vhi, out, njb);
}

// Round 22
// 64.433 us; speedup vs baseline: 1.0546x; 1.0546x over previous
//
#include <hip/hip_runtime.h>
#include <hip/hip_bf16.h>

// GAT layer, N=4096, FIN=512, H=4 heads, F=64.
// FINAL (== R20, measured best 64.5us; R21's unroll-8 regressed -> ILP lever
// maxed at 4). Journey: 354.8 (R1 f32 baseline) -> 64.5 via: rank-1 score
// decomposition + no-max-sub softmax (exact: scores bounded), bitmask A
// (64MB->2MB), fused GEMM+scores+V-transpose overlapped with A-pack, MFMA
// PV with trunc-packed bf16 P (error-transparent vs f32 score noise),
// bf16 partials (32MB HBM saved), K3 64-row ILP + unroll-4.
//   K01: blocks<512 = GEMM 32x64/2x4-micro + scores + u16-padded V-transpose;
//        blocks>=512 = grid-stride ballot mask-pack.
//   K3:  64 rows/block, 20 MFMA/cc, trunc-packed P, raw v_exp_f32,
//        no max-subtraction; bf16 partials; cc-unroll 4.
//   K4:  combine njb bf16 partials, normalize, ELU.
// ws: pacc16 njb*2MB | f1h | f2h | Vhi 2MB | plsum | Ab 2MB. njb: 8 else 4.

#define NN   4096
#define FIN  512
#define H    4
#define F    64
#define HF   256
#define LOG2E 1.44269504088896340736f

typedef __attribute__((ext_vector_type(4))) float f32x4;
typedef __attribute__((ext_vector_type(8))) short short8;

union U8 { short8 s; unsigned int w[4]; };

// ---------------- K01: fused (GEMM+scores+transpose) | mask-pack ----------
// grid 1536: blocks 0..511 = gemm (bi = b&127, h = b>>7), 512..1535 = pack.
__global__ __launch_bounds__(256) void gemm_scores_pack(
        const float* __restrict__ X, const float* __restrict__ W,
        const float* __restrict__ a_src, const float* __restrict__ a_dst,
        const int* __restrict__ A,
        float* __restrict__ f1h, float* __restrict__ f2h,
        unsigned short* __restrict__ Vhi,
        unsigned long long* __restrict__ Ab) {
    if (blockIdx.x >= 512) {
        const int pb   = blockIdx.x - 512;                    // 0..1023
        const int gw   = (pb * 256 + threadIdx.x) >> 6;
        const int lane = threadIdx.x & 63;
        const int nchunk = NN * NN / 64;                      // 262144
        for (int c = gw; c < nchunk; c += 4096) {
            int a = A[(size_t)c * 64 + lane];
            unsigned long long m = __ballot(a != 0);
            if (lane == 0) Ab[c] = m;
        }
        return;
    }

    __shared__ float Ast[32][34];            // [k][m]
    __shared__ float Bs[32][64];             // [k][n]
    __shared__ unsigned short Vt[64][40];    // [f][n]

    const int bi = blockIdx.x & 127, h = blockIdx.x >> 7;
    const int t  = threadIdx.x;
    const int tx = t & 15, ty = t >> 4;

    float acc[2][4];
#pragma unroll
    for (int r = 0; r < 2; ++r)
#pragma unroll
        for (int c = 0; c < 4; ++c) acc[r][c] = 0.f;

    const int ar = t >> 3, ak = (t & 7) * 4;
    const int bk = t >> 3, bn = (t & 7) * 8;

    const float* Ap = X + (size_t)(bi * 32 + ar) * FIN + ak;
    const float* Bp = W + (size_t)bk * HF + h * F + bn;

    for (int k0 = 0; k0 < FIN; k0 += 32) {
        float4 av  = *(const float4*)(Ap + k0);
        float4 bv0 = *(const float4*)(Bp + (size_t)k0 * HF);
        float4 bv1 = *(const float4*)(Bp + (size_t)k0 * HF + 4);
        __syncthreads();
        Ast[ak + 0][ar] = av.x;
        Ast[ak + 1][ar] = av.y;
        Ast[ak + 2][ar] = av.z;
        Ast[ak + 3][ar] = av.w;
        *(float4*)&Bs[bk][bn] = bv0;
        *(float4*)&Bs[bk][bn + 4] = bv1;
        __syncthreads();
#pragma unroll
        for (int kk = 0; kk < 32; ++kk) {
            float2 a2 = *(const float2*)&Ast[kk][ty * 2];
            float4 b4 = *(const float4*)&Bs[kk][tx * 4];
            acc[0][0] += a2.x * b4.x; acc[0][1] += a2.x * b4.y;
            acc[0][2] += a2.x * b4.z; acc[0][3] += a2.x * b4.w;
            acc[1][0] += a2.y * b4.x; acc[1][1] += a2.y * b4.y;
            acc[1][2] += a2.y * b4.z; acc[1][3] += a2.y * b4.w;
        }
    }

    // scores: per-row dot with a_src/a_dst, reduce over 16 tx lanes
    float4 as4 = *(const float4*)(a_src + h * F + tx * 4);
    float4 ad4 = *(const float4*)(a_dst + h * F + tx * 4);
#pragma unroll
    for (int r = 0; r < 2; ++r) {
        float s1 = acc[r][0] * as4.x + acc[r][1] * as4.y
                 + acc[r][2] * as4.z + acc[r][3] * as4.w;
        float s2 = acc[r][0] * ad4.x + acc[r][1] * ad4.y
                 + acc[r][2] * ad4.z + acc[r][3] * ad4.w;
#pragma unroll
        for (int off = 1; off < 16; off <<= 1) {
            s1 += __shfl_xor(s1, off, 16);
            s2 += __shfl_xor(s2, off, 16);
        }
        if (tx == 0) {
            const int n = bi * 32 + ty * 2 + r;
            f1h[h * NN + n] = s1 * LOG2E;
            f2h[h * NN + n] = s2 * LOG2E;
        }
    }

    // transposed bf16 V via LDS bounce
    __syncthreads();
#pragma unroll
    for (int r = 0; r < 2; ++r)
#pragma unroll
        for (int c = 0; c < 4; ++c) {
            __hip_bfloat16 b = __float2bfloat16(acc[r][c]);
            Vt[tx * 4 + c][ty * 2 + r] = __builtin_bit_cast(unsigned short, b);
        }
    __syncthreads();
    {
        const int f = t >> 2, ch = t & 3;
        short8 v = *(const short8*)&Vt[f][ch * 8];
        *(short8*)&Vhi[(size_t)(h * F + f) * NN + bi * 32 + ch * 8] = v;
    }
}

// ---------------- K3: MFMA fused attention (bf16 partials) ----------------
// grid (64, njb): ib = 64-row block (4 rowtiles), jb = JLEN strip. wave=head.
template <int JLEN>
__global__ __launch_bounds__(256) void gat_attn_mfma(
        const unsigned int* __restrict__ Ab32,
        const unsigned short* __restrict__ Vhi,
        const float* __restrict__ f1h, const float* __restrict__ f2h,
        unsigned short* __restrict__ pacc16, float* __restrict__ plsum) {
    constexpr int NCC = JLEN / 32;
    const int ib = blockIdx.x, jb = blockIdx.y;
    const int h    = threadIdx.x >> 6;
    const int lane = threadIdx.x & 63;
    const int il = lane & 15;        // MFMA A row / B,C/D col
    const int kg = lane >> 4;        // k-group
    const int sh = kg * 8;
    const int ibase = ib * 64 + il;

    float c[4];
#pragma unroll
    for (int rt = 0; rt < 4; ++rt) c[rt] = f1h[h * NN + ibase + rt * 16];

    const unsigned int* abp[4];
#pragma unroll
    for (int rt = 0; rt < 4; ++rt)
        abp[rt] = Ab32 + (size_t)(ibase + rt * 16) * (NN / 32) + jb * (JLEN / 32);

    const float* f2b = f2h + (size_t)h * NN + jb * JLEN + sh;

    const unsigned short* vb[4];
#pragma unroll
    for (int ft = 0; ft < 4; ++ft)
        vb[ft] = Vhi + (size_t)(h * F + ft * 16 + il) * NN + jb * JLEN + sh;

    f32x4 acc[4][4], lac[4];
#pragma unroll
    for (int rt = 0; rt < 4; ++rt) {
        lac[rt] = (f32x4){0.f, 0.f, 0.f, 0.f};
#pragma unroll
        for (int ft = 0; ft < 4; ++ft) acc[rt][ft] = (f32x4){0.f, 0.f, 0.f, 0.f};
    }

    short8 ones;
#pragma unroll
    for (int e = 0; e < 8; ++e) ones[e] = (short)0x3F80;   // bf16 1.0

#pragma unroll 4
    for (int cc = 0; cc < NCC; ++cc) {
        unsigned int m[4];
#pragma unroll
        for (int rt = 0; rt < 4; ++rt) m[rt] = abp[rt][cc] >> sh;

        float4 ga = *(const float4*)(f2b + cc * 32);
        float4 gb = *(const float4*)(f2b + cc * 32 + 4);
        float gv[8] = {ga.x, ga.y, ga.z, ga.w, gb.x, gb.y, gb.z, gb.w};

        short8 bh[4];
#pragma unroll
        for (int ft = 0; ft < 4; ++ft)
            bh[ft] = *reinterpret_cast<const short8*>(vb[ft] + cc * 32);

#pragma unroll
        for (int rt = 0; rt < 4; ++rt) {
            float pf[8];
#pragma unroll
            for (int e = 0; e < 8; ++e) {
                float s = c[rt] + gv[e];
                s = fmaxf(s, 0.2f * s);                 // leaky relu
                float q = __builtin_amdgcn_exp2f(s);    // raw v_exp_f32
                pf[e] = ((m[rt] >> e) & 1u) ? q : 0.f;
            }
            U8 pa;
#pragma unroll
            for (int e = 0; e < 8; e += 2)
                pa.w[e >> 1] = __builtin_amdgcn_perm(__float_as_uint(pf[e + 1]),
                                                     __float_as_uint(pf[e]),
                                                     0x07060302u);
#pragma unroll
            for (int ft = 0; ft < 4; ++ft)
                acc[rt][ft] = __builtin_amdgcn_mfma_f32_16x16x32_bf16(
                    pa.s, bh[ft], acc[rt][ft], 0, 0, 0);
            lac[rt] = __builtin_amdgcn_mfma_f32_16x16x32_bf16(
                pa.s, ones, lac[rt], 0, 0, 0);
        }
    }

    // C/D layout: col = lane&15, row = (lane>>4)*4 + reg. RNE-bf16 partials.
    unsigned short* pb = pacc16 + (size_t)jb * NN * HF + (size_t)(ib * 64) * HF;
#pragma unroll
    for (int rt = 0; rt < 4; ++rt)
#pragma unroll
        for (int ft = 0; ft < 4; ++ft)
#pragma unroll
            for (int r = 0; r < 4; ++r) {
                __hip_bfloat16 b = __float2bfloat16(acc[rt][ft][r]);
                pb[(rt * 16 + kg * 4 + r) * HF + h * F + ft * 16 + il] =
                    __builtin_bit_cast(unsigned short, b);
            }

    if (il == 0) {   // ones-MFMA: every col holds the row sum; use col 0
#pragma unroll
        for (int rt = 0; rt < 4; ++rt)
#pragma unroll
            for (int r = 0; r < 4; ++r)
                plsum[(size_t)jb * NN * H
                      + (size_t)(ib * 64 + rt * 16 + kg * 4 + r) * H + h] = lac[rt][r];
    }
}

// ---------------- K4: combine bf16 partials, normalize, ELU ----------
__global__ __launch_bounds__(256) void finalize(
        const unsigned short* __restrict__ pacc16,
        const float* __restrict__ plsum,
        const unsigned short* __restrict__ Vhi, float* __restrict__ out,
        int njb) {
    const int gid4 = blockIdx.x * 256 + threadIdx.x;   // 0 .. NN*HF/4-1
    const int i = gid4 >> 6, q = gid4 & 63;
    const int h = q >> 4;
    float av[4] = {0.f, 0.f, 0.f, 0.f};
    float l = 0.f;
    for (int jb = 0; jb < njb; ++jb) {
        ushort4 p = *(const ushort4*)&pacc16[(size_t)jb * NN * HF
                                             + (size_t)i * HF + q * 4];
        av[0] += __uint_as_float((unsigned)p.x << 16);
        av[1] += __uint_as_float((unsigned)p.y << 16);
        av[2] += __uint_as_float((unsigned)p.z << 16);
        av[3] += __uint_as_float((unsigned)p.w << 16);
        l += plsum[(size_t)jb * NN * H + (size_t)i * H + h];
    }
    if (l == 0.f) {   // empty row: reference softmax degenerates to uniform
#pragma unroll
        for (int c = 0; c < 4; ++c) {
            const unsigned short* col = Vhi + (size_t)(q * 4 + c) * NN;
            float s = 0.f;
            for (int j = 0; j < NN; ++j)
                s += __uint_as_float(((unsigned int)col[j]) << 16);
            av[c] = s;
        }
        l = (float)NN;
    }
    const float rl = 1.0f / l;
    float4 o;
    float* op = &o.x;
#pragma unroll
    for (int c = 0; c < 4; ++c) {
        float v = av[c] * rl;
        op[c] = (v > 0.f) ? v : (__builtin_amdgcn_exp2f(v * LOG2E) - 1.f);
    }
    *(float4*)&out[(size_t)i * HF + q * 4] = o;
}

// ---------------- launch ----------------
extern "C" void kernel_launch(void* const* d_in, const int* in_sizes, int n_in,
                              void* d_out, int out_size, void* d_ws, size_t ws_size,
                              hipStream_t stream) {
    const float* X     = (const float*)d_in[0];
    const int*   A     = (const int*)d_in[1];
    const float* W     = (const float*)d_in[2];
    const float* a_src = (const float*)d_in[3];
    const float* a_dst = (const float*)d_in[4];
    float* out = (float*)d_out;

    // ws: pacc16 njb*NN*HF*2 | f1h,f2h | Vhi HF*NN*2 | plsum | Ab NN*NN/8
    const size_t fixed = (size_t)2 * NN * H * 4 + (size_t)HF * NN * 2
                       + (size_t)NN * NN / 8;
    auto need = [&](int njb) {
        return (size_t)njb * NN * HF * 2 + (size_t)njb * NN * H * 4 + fixed;
    };
    const int njb = (ws_size >= need(8)) ? 8 : 4;   // deterministic in ws_size

    unsigned short* pacc16 = (unsigned short*)d_ws;
    float* f1h  = (float*)(pacc16 + (size_t)njb * NN * HF);
    float* f2h  = f1h + (size_t)NN * H;
    unsigned short* Vhi = (unsigned short*)(f2h + (size_t)NN * H);
    float* plsum = (float*)(Vhi + (size_t)HF * NN);
    unsigned long long* Ab = (unsigned long long*)(plsum + (size_t)njb * NN * H);

    gemm_scores_pack<<<1536, 256, 0, stream>>>(X, W, a_src, a_dst, A,
                                               f1h, f2h, Vhi, Ab);
    if (njb == 8)
        gat_attn_mfma<512><<<dim3(64, 8), 256, 0, stream>>>(
            (const unsigned int*)Ab, Vhi, f1h, f2h, pacc16, plsum);
    else
        gat_attn_mfma<1024><<<dim3(64, 4), 256, 0, stream>>>(
            (const unsigned int*)Ab, Vhi, f1h, f2h, pacc16, plsum);
    finalize<<<NN * HF / 4 / 256, 256, 0, stream>>>(pacc16, plsum, Vhi, out, njb);
}